// Round 17
// baseline (224.196 us; speedup 1.0000x reference)
//
#include <hip/hip_runtime.h>

// ---------------------------------------------------------------------------
// GCN 2-layer forward on MI355X.
//  out = Ahat( relu( Ahat (X W1) + b1 ) W2 ) + b2,  Ahat = D^-1/2 (A+I) D^-1/2
// R17: gemm2 DELETED — fused into agg1. g2 = dis.*(h1@W2) is per-node, so
//      agg1's wave (which ends holding its node's h1 row) writes h1 to a
//      4-row LDS tile, one barrier, then each wave computes a 16-col slice
//      of the block's 4 g2 rows with 4 MFMAs (B-frags from L1-hot wt2).
//      Saves gemm2 dispatch + h1 25.6MB write + 25.6MB read; agg1 write
//      halves (12.8MB g2). Everything else = R16 (206us best).
// ---------------------------------------------------------------------------

constexpr int IN_CH  = 256;
constexpr int HID    = 128;
constexpr int OUT_CH = 64;
constexpr int EPB = 4096;         // edges per block in hist/scatter

typedef __attribute__((ext_vector_type(8))) short short8;
typedef __attribute__((ext_vector_type(4))) float f32x4;

union F8 {                       // one MFMA A/B fragment: 8 bf16
    short8 v;
    unsigned short u[8];
    uint4  q;
};

// ---- bf16 helpers (RNE) ----
__device__ inline unsigned short f2b(float f) {
    unsigned u = __float_as_uint(f);
    u += 0x7fffu + ((u >> 16) & 1u);
    return (unsigned short)(u >> 16);
}
__device__ inline unsigned pack_bf16(float a, float b) {
    unsigned ua = __float_as_uint(a); ua += 0x7fffu + ((ua >> 16) & 1u);
    unsigned ub = __float_as_uint(b); ub += 0x7fffu + ((ub >> 16) & 1u);
    return (ua >> 16) | (ub & 0xffff0000u);
}
__device__ inline float2 unpack_bf16(unsigned v) {
    return make_float2(__uint_as_float(v << 16), __uint_as_float(v & 0xffff0000u));
}

// ---------------- CSR build (bucket radix, LDS atomics only) ----------------

__global__ __launch_bounds__(256) void bucket_hist(
    const int* __restrict__ dst, int* __restrict__ blockhist,
    const float* __restrict__ W1, unsigned short* __restrict__ wt1,
    const float* __restrict__ W2, unsigned short* __restrict__ wt2,
    int E, int NB, int NBUCK) {
    __shared__ int lbin[512];
    for (int l = threadIdx.x; l < 512; l += 256) lbin[l] = 0;
    __syncthreads();
    constexpr int NWT1 = IN_CH * HID;      // 32768
    constexpr int NWT2 = HID * OUT_CH;     // 8192
    for (int i = blockIdx.x * 256 + threadIdx.x; i < NWT1 + NWT2; i += gridDim.x * 256) {
        if (i < NWT1) {
            int c = i >> 8, k = i & 255;               // wt1[c*256+k] = W1[k][c]
            wt1[i] = f2b(W1[k * HID + c]);
        } else {
            int j = i - NWT1;
            int c = j >> 7, k = j & 127;               // wt2[c*128+k] = W2[k][c]
            wt2[j] = f2b(W2[k * OUT_CH + c]);
        }
    }
    int base = blockIdx.x * EPB;
    #pragma unroll 4
    for (int j = 0; j < EPB / 256; ++j) {
        int e = base + j * 256 + threadIdx.x;
        if (e < E) atomicAdd(&lbin[((unsigned)dst[e]) >> 8], 1);
    }
    __syncthreads();
    for (int l = threadIdx.x; l < NBUCK; l += 256)
        blockhist[l * NB + blockIdx.x] = lbin[l];   // bucket-major
}

__global__ __launch_bounds__(1024) void scan_partial_kernel(
    const int* __restrict__ in, int* __restrict__ partial, int len) {
    __shared__ int sh[1024];
    int i = blockIdx.x * 1024 + threadIdx.x;
    sh[threadIdx.x] = (i < len) ? in[i] : 0;
    __syncthreads();
    for (int ofs = 512; ofs > 0; ofs >>= 1) {
        if (threadIdx.x < ofs) sh[threadIdx.x] += sh[threadIdx.x + ofs];
        __syncthreads();
    }
    if (threadIdx.x == 0) partial[blockIdx.x] = sh[0];
}

__global__ __launch_bounds__(1024) void scan_topfinal_kernel(
    const int* __restrict__ in, const int* __restrict__ partial,
    int nchunks, int* __restrict__ out, int L) {
    __shared__ int top[1024];
    __shared__ int sh[1024];
    int t = threadIdx.x;
    top[t] = (t < nchunks) ? partial[t] : 0;
    int i = blockIdx.x * 1024 + t;
    int v = (i < L) ? in[i] : 0;
    sh[t] = v;
    __syncthreads();
    for (int ofs = 1; ofs < 1024; ofs <<= 1) {
        int a = (t >= ofs) ? top[t - ofs] : 0;
        int b = (t >= ofs) ? sh[t - ofs] : 0;
        __syncthreads();
        top[t] += a; sh[t] += b;
        __syncthreads();
    }
    int base = (blockIdx.x > 0) ? top[blockIdx.x - 1] : 0;   // exclusive chunk base
    if (i < L) out[i] = base + sh[t] - v;                    // exclusive
    if (blockIdx.x == 0 && t == 0) out[L] = top[nchunks - 1];  // grand total == E
}

__global__ __launch_bounds__(256) void bucket_scatter(
    const int* __restrict__ src, const int* __restrict__ dst,
    const int* __restrict__ flatscan, unsigned* __restrict__ sorted,
    int E, int NB, int NBUCK) {
    __shared__ int cur[512];
    for (int l = threadIdx.x; l < NBUCK; l += 256)
        cur[l] = flatscan[l * NB + blockIdx.x];
    __syncthreads();
    int base = blockIdx.x * EPB;
    #pragma unroll 4
    for (int j = 0; j < EPB / 256; ++j) {
        int e = base + j * 256 + threadIdx.x;
        if (e < E) {
            int d = dst[e];
            int bk = ((unsigned)d) >> 8;
            int slot = atomicAdd(&cur[bk], 1);
            sorted[slot] = (((unsigned)(d & 255)) << 24) | (unsigned)src[e];
        }
    }
}

__global__ __launch_bounds__(256) void bucket_finalize(
    const unsigned* __restrict__ sorted, const int* __restrict__ flatscan,
    int* __restrict__ csr_src, int* __restrict__ row_ptr, float* __restrict__ dis,
    int NB, int n) {
    __shared__ int cnt[256];
    __shared__ int sh[256];
    __shared__ int cur[256];
    int b = blockIdx.x;
    int t = threadIdx.x;
    int ebeg = flatscan[b * NB];
    int eend = flatscan[(b + 1) * NB];
    cnt[t] = 0;
    __syncthreads();
    for (int e = ebeg + t; e < eend; e += 256)
        atomicAdd(&cnt[sorted[e] >> 24], 1);
    __syncthreads();
    int v = cnt[t];
    sh[t] = v;
    __syncthreads();
    for (int ofs = 1; ofs < 256; ofs <<= 1) {
        int tv = (t >= ofs) ? sh[t - ofs] : 0;
        __syncthreads();
        sh[t] += tv;
        __syncthreads();
    }
    int excl = sh[t] - v;
    int node = b * 256 + t;
    if (node <= n) row_ptr[node] = ebeg + excl;
    if (node < n)  dis[node] = rsqrtf(1.0f + (float)v);
    cur[t] = excl;
    __syncthreads();
    for (int e = ebeg + t; e < eend; e += 256) {
        unsigned s = sorted[e];
        int pos = atomicAdd(&cur[s >> 24], 1);
        csr_src[ebeg + pos] = (int)(s & 0xFFFFFFu);
    }
}

// ---------------- GEMM 1 (R16: reg-prefetch body + coalesced epilogue) -------

__global__ __launch_bounds__(512) void gemm1_mfma(
    const float* __restrict__ X, const unsigned short* __restrict__ Wt,
    const float* __restrict__ dis, unsigned short* __restrict__ G, int n) {
    constexpr int K = 256, LP = 20, NS = 8;
    __shared__ unsigned xs[2][128 * LP];          // 20 KB; reused by epilogue

    int tid  = threadIdx.x;
    int lane = tid & 63;
    int w    = tid >> 6;
    int wm = w >> 2, wn = w & 3;
    int rowbase = blockIdx.x * 128 + wm * 64;
    int colbase = wn * 32;
    int la = lane & 15, lb = lane >> 4;

    int srow = tid >> 2, sq = tid & 3;
    int grow = blockIdx.x * 128 + srow;
    if (grow >= n) grow = n - 1;
    const float* xrow = X + (size_t)grow * K + sq * 8;
    int sofs = srow * LP + sq * 4;                // uint offset in xs

    float4 pf0, pf1;
    #define G1_LOAD(ks) { const float* p_ = xrow + (ks) * 32;                 \
        pf0 = *(const float4*)(p_); pf1 = *(const float4*)(p_ + 4); }
    #define G1_WRITE(buf) { uint4 o_;                                         \
        o_.x = pack_bf16(pf0.x, pf0.y); o_.y = pack_bf16(pf0.z, pf0.w);       \
        o_.z = pack_bf16(pf1.x, pf1.y); o_.w = pack_bf16(pf1.z, pf1.w);       \
        *(uint4*)&xs[buf][sofs] = o_; }

    f32x4 acc[4][2];
    #pragma unroll
    for (int m = 0; m < 4; ++m)
        #pragma unroll
        for (int nn = 0; nn < 2; ++nn) acc[m][nn] = (f32x4){0.f, 0.f, 0.f, 0.f};

    G1_LOAD(0);
    G1_WRITE(0);
    G1_LOAD(1);
    __syncthreads();

    #pragma unroll
    for (int ks = 0; ks < NS; ++ks) {
        int cur = ks & 1;
        if (ks + 1 < NS) G1_WRITE(cur ^ 1);       // regs hold slab ks+1
        if (ks + 2 < NS) G1_LOAD(ks + 2);
        F8 a[4], b[2];
        #pragma unroll
        for (int m = 0; m < 4; ++m)
            a[m].q = *(const uint4*)&xs[cur][(wm * 64 + m * 16 + la) * LP + lb * 4];
        #pragma unroll
        for (int nn = 0; nn < 2; ++nn) {
            int col = colbase + nn * 16 + la;
            b[nn].q = *(const uint4*)(Wt + (size_t)col * K + ks * 32 + lb * 8);
        }
        #pragma unroll
        for (int m = 0; m < 4; ++m)
            #pragma unroll
            for (int nn = 0; nn < 2; ++nn)
                acc[m][nn] = __builtin_amdgcn_mfma_f32_16x16x32_bf16(
                    a[m].v, b[nn].v, acc[m][nn], 0, 0, 0);
        __syncthreads();
    }
    #undef G1_LOAD
    #undef G1_WRITE

    // ---- epilogue: LDS transpose -> coalesced 32B stores, 2 row-half passes
    unsigned short* eps = (unsigned short*)&xs[0][0];
    constexpr int ES = 136;                       // ushort stride (272B, 16B-aligned)
    #pragma unroll
    for (int p = 0; p < 2; ++p) {
        __syncthreads();
        if (wm == p) {
            #pragma unroll
            for (int m = 0; m < 4; ++m) {
                int lr0 = m * 16 + lb * 4;
                int r0 = rowbase + lr0;           // rowbase already includes wm*64
                float dv[4];
                #pragma unroll
                for (int r = 0; r < 4; ++r) dv[r] = (r0 + r < n) ? dis[r0 + r] : 0.f;
                #pragma unroll
                for (int nn = 0; nn < 2; ++nn) {
                    int col = colbase + nn * 16 + la;
                    #pragma unroll
                    for (int r = 0; r < 4; ++r)
                        eps[(lr0 + r) * ES + col] = f2b(acc[m][nn][r] * dv[r]);
                }
            }
        }
        __syncthreads();
        {
            int lrow = tid >> 3, seg = tid & 7;   // 64 rows x 8 segs x 16 ushorts
            int gr = blockIdx.x * 128 + p * 64 + lrow;
            if (gr < n) {
                const uint4* s = (const uint4*)&eps[lrow * ES + seg * 16];
                uint4 v0 = s[0], v1 = s[1];
                uint4* d = (uint4*)(G + (size_t)gr * HID + seg * 16);
                d[0] = v0; d[1] = v1;
            }
        }
    }
}

// ---------------- Fused agg1 + gemm2 ----------------------------------------
// Per block: 4 waves = 4 nodes. Gather phase (quarter-wave, 16 in flight)
// computes h1 row per wave -> bf16 into LDS hrow[4 rows]. One barrier. Then
// each wave computes a 16-col slice of ALL 4 nodes' g2 = dis.*(h1 @ W2) via
// 4 MFMAs (A rows 0-3 valid, 4-15 garbage/unused; B from L1-hot wt2).

__device__ inline void acc8(float* s, uint4 u) {
    float2 t;
    t = unpack_bf16(u.x); s[0] += t.x; s[1] += t.y;
    t = unpack_bf16(u.y); s[2] += t.x; s[3] += t.y;
    t = unpack_bf16(u.z); s[4] += t.x; s[5] += t.y;
    t = unpack_bf16(u.w); s[6] += t.x; s[7] += t.y;
}

__global__ __launch_bounds__(256) void agg1_fused(
    const unsigned* __restrict__ G, const int* __restrict__ row_ptr,
    const int* __restrict__ csr_src, const float* __restrict__ dis,
    const float* __restrict__ b1, const unsigned short* __restrict__ Wt2,
    unsigned short* __restrict__ G2, int n) {
    constexpr int HS = 136;                         // hrow ushort stride (272B)
    __shared__ __align__(16) unsigned short hrow[16 * HS];   // rows 4-15 garbage

    int wv   = threadIdx.x >> 6;                    // wave id 0..3
    int lane = threadIdx.x & 63;
    int nodebase = blockIdx.x * 4;
    int wid = nodebase + wv;
    int wc  = wid < n ? wid : n - 1;                // clamp (no early return)
    int q = lane >> 4, hl = lane & 15;
    const char* Gb = (const char*)G;                // g1 row = 256B
    unsigned lofs = (unsigned)(hl << 4);
    float s0[8] = {0,0,0,0,0,0,0,0}, s1[8] = {0,0,0,0,0,0,0,0};
    float s2[8] = {0,0,0,0,0,0,0,0}, s3[8] = {0,0,0,0,0,0,0,0};
    int beg = row_ptr[wc], end = row_ptr[wc + 1];
    for (int base = beg; base < end; base += 64) {
        int m = end - base; if (m > 64) m = 64;
        int idx = csr_src[base + (lane < m ? lane : m - 1)];
        int j = 0;
        for (; j + 16 <= m; j += 16) {
            unsigned o0 = ((unsigned)__shfl(idx, j +      q) << 8) + lofs;
            unsigned o1 = ((unsigned)__shfl(idx, j +  4 + q) << 8) + lofs;
            unsigned o2 = ((unsigned)__shfl(idx, j +  8 + q) << 8) + lofs;
            unsigned o3 = ((unsigned)__shfl(idx, j + 12 + q) << 8) + lofs;
            uint4 u0 = *(const uint4*)(Gb + o0);
            uint4 u1 = *(const uint4*)(Gb + o1);
            uint4 u2 = *(const uint4*)(Gb + o2);
            uint4 u3 = *(const uint4*)(Gb + o3);
            acc8(s0, u0); acc8(s1, u1); acc8(s2, u2); acc8(s3, u3);
        }
        for (; j + 4 <= m; j += 4) {
            unsigned o0 = ((unsigned)__shfl(idx, j + q) << 8) + lofs;
            uint4 u0 = *(const uint4*)(Gb + o0);
            acc8(s0, u0);
        }
        int rem = m - j;                          // 0..3
        if (rem) {
            int ii = __shfl(idx, j + (q < rem ? q : 0));
            if (q < rem) {
                uint4 u = *(const uint4*)(Gb + (((unsigned)ii << 8) + lofs));
                acc8(s0, u);
            }
        }
    }
    #pragma unroll
    for (int c = 0; c < 8; ++c) s0[c] += s1[c] + s2[c] + s3[c];
    #pragma unroll
    for (int c = 0; c < 8; ++c) {
        s0[c] += __shfl_xor(s0[c], 16);
        s0[c] += __shfl_xor(s0[c], 32);
    }
    uint4 su = *(const uint4*)(Gb + (((unsigned)wc << 8) + lofs));   // self
    acc8(s0, su);
    float d = dis[wc];
    float bb[8];
    *(float4*)&bb[0] = ((const float4*)b1)[hl * 2];
    *(float4*)&bb[4] = ((const float4*)b1)[hl * 2 + 1];
    float o[8];
    #pragma unroll
    for (int c = 0; c < 8; ++c) o[c] = fmaxf(fmaf(s0[c], d, bb[c]), 0.f);
    if (q == 0) {                                 // write h1 row (bf16) to LDS
        uint4 ou;
        ou.x = pack_bf16(o[0], o[1]);
        ou.y = pack_bf16(o[2], o[3]);
        ou.z = pack_bf16(o[4], o[5]);
        ou.w = pack_bf16(o[6], o[7]);
        *(uint4*)&hrow[wv * HS + hl * 8] = ou;
    }
    __syncthreads();

    // ---- per-node matvec via MFMA: wave wv -> output cols wv*16..wv*16+16
    int la2 = lane & 15, lb2 = lane >> 4;
    f32x4 acc = (f32x4){0.f, 0.f, 0.f, 0.f};
    #pragma unroll
    for (int ks = 0; ks < 4; ++ks) {
        F8 a, b;
        a.q = *(const uint4*)&hrow[la2 * HS + ks * 32 + lb2 * 8];
        b.q = *(const uint4*)(Wt2 + (size_t)(wv * 16 + la2) * HID + ks * 32 + lb2 * 8);
        acc = __builtin_amdgcn_mfma_f32_16x16x32_bf16(a.v, b.v, acc, 0, 0, 0);
    }
    // C/D: col = lane&15, row = (lane>>4)*4 + reg -> rows 0-3 live on lanes 0-15
    if (lb2 == 0) {
        #pragma unroll
        for (int r = 0; r < 4; ++r) {
            int node = nodebase + r;
            if (node < n)
                G2[(size_t)node * OUT_CH + wv * 16 + la2] = f2b(acc[r] * dis[node]);
        }
    }
}

// ---------------- Aggregation 2: out = dis .* (self+gather) + b2 -------------

__device__ inline void acc4u(float* s, uint2 u) {
    float2 t;
    t = unpack_bf16(u.x); s[0] += t.x; s[1] += t.y;
    t = unpack_bf16(u.y); s[2] += t.x; s[3] += t.y;
}

__global__ __launch_bounds__(256) void agg2_kernel(
    const unsigned short* __restrict__ G, const int* __restrict__ row_ptr,
    const int* __restrict__ csr_src, const float* __restrict__ dis,
    const float* __restrict__ b2, float* __restrict__ out, int n) {
    int wid = (blockIdx.x * blockDim.x + threadIdx.x) >> 6;
    int lane = threadIdx.x & 63;
    if (wid >= n) return;
    int q = lane >> 4, hl = lane & 15;
    const char* Gb = (const char*)G;              // row = 128B
    unsigned lofs = (unsigned)(hl << 3);
    float s0[4] = {0,0,0,0}, s1[4] = {0,0,0,0}, s2[4] = {0,0,0,0}, s3[4] = {0,0,0,0};
    int beg = row_ptr[wid], end = row_ptr[wid + 1];
    for (int base = beg; base < end; base += 64) {
        int m = end - base; if (m > 64) m = 64;
        int idx = csr_src[base + (lane < m ? lane : m - 1)];
        int j = 0;
        for (; j + 16 <= m; j += 16) {
            unsigned o0 = ((unsigned)__shfl(idx, j +      q) << 7) + lofs;
            unsigned o1 = ((unsigned)__shfl(idx, j +  4 + q) << 7) + lofs;
            unsigned o2 = ((unsigned)__shfl(idx, j +  8 + q) << 7) + lofs;
            unsigned o3 = ((unsigned)__shfl(idx, j + 12 + q) << 7) + lofs;
            uint2 u0 = *(const uint2*)(Gb + o0);
            uint2 u1 = *(const uint2*)(Gb + o1);
            uint2 u2 = *(const uint2*)(Gb + o2);
            uint2 u3 = *(const uint2*)(Gb + o3);
            acc4u(s0, u0); acc4u(s1, u1); acc4u(s2, u2); acc4u(s3, u3);
        }
        for (; j + 4 <= m; j += 4) {
            unsigned o0 = ((unsigned)__shfl(idx, j + q) << 7) + lofs;
            uint2 u0 = *(const uint2*)(Gb + o0);
            acc4u(s0, u0);
        }
        int rem = m - j;
        if (rem) {
            int ii = __shfl(idx, j + (q < rem ? q : 0));
            if (q < rem) {
                uint2 u = *(const uint2*)(Gb + (((unsigned)ii << 7) + lofs));
                acc4u(s0, u);
            }
        }
    }
    #pragma unroll
    for (int c = 0; c < 4; ++c) s0[c] += s1[c] + s2[c] + s3[c];
    #pragma unroll
    for (int c = 0; c < 4; ++c) {
        s0[c] += __shfl_xor(s0[c], 16);
        s0[c] += __shfl_xor(s0[c], 32);
    }
    uint2 su = *(const uint2*)(Gb + (((unsigned)wid << 7) + lofs));   // self
    acc4u(s0, su);
    float d = dis[wid];
    float4 bb = ((const float4*)b2)[hl];
    if (q == 0) {
        float4 o;
        o.x = fmaf(s0[0], d, bb.x);
        o.y = fmaf(s0[1], d, bb.y);
        o.z = fmaf(s0[2], d, bb.z);
        o.w = fmaf(s0[3], d, bb.w);
        ((float4*)out)[(size_t)wid * 16 + hl] = o;
    }
}

// ---------------- launch ----------------

extern "C" void kernel_launch(void* const* d_in, const int* in_sizes, int n_in,
                              void* d_out, int out_size, void* d_ws, size_t ws_size,
                              hipStream_t stream) {
    const float* x  = (const float*)d_in[0];
    const int*   ei = (const int*)d_in[1];
    const float* W1 = (const float*)d_in[2];
    const float* b1 = (const float*)d_in[3];
    const float* W2 = (const float*)d_in[4];
    const float* b2 = (const float*)d_in[5];
    float* out = (float*)d_out;

    int n = in_sizes[0] / IN_CH;       // 100000
    int E = in_sizes[1] / 2;           // 1600000
    const int* srcv = ei;
    const int* dstv = ei + E;

    int NB    = (E + EPB - 1) / EPB;   // 391 edge-blocks
    int NBUCK = (n + 255) >> 8;        // 391 buckets (256 nodes each)
    int L     = NBUCK * NB;
    int nchunks = (L + 1023) / 1024;   // 150

    char* w = (char*)d_ws;
    unsigned short* g1 = (unsigned short*)w;  w += (size_t)n * HID * 2;     // 25.6 MB
    unsigned short* g2 = (unsigned short*)w;  w += (size_t)n * OUT_CH * 2;  // 12.8 MB (separate: fused kernel reads g1 while writing g2)
    unsigned short* wt1 = (unsigned short*)w; w += (size_t)IN_CH * HID * 2;
    unsigned short* wt2 = (unsigned short*)w; w += (size_t)HID * OUT_CH * 2;
    int*      blockhist = (int*)w; w += (size_t)L * 4;
    int*      flatscan  = (int*)w; w += (size_t)(L + 1) * 4;
    int*      partial   = (int*)w; w += (size_t)1024 * 4;
    unsigned* sorted    = (unsigned*)w; w += (size_t)E * 4;                 // 6.4 MB
    int*      csr       = (int*)w; w += (size_t)E * 4;                      // 6.4 MB
    int*      row_ptr   = (int*)w; w += (size_t)(n + 1) * 4;
    float*    dis       = (float*)w; w += (size_t)n * 4;

    bucket_hist<<<NB, 256, 0, stream>>>(dstv, blockhist, W1, wt1, W2, wt2, E, NB, NBUCK);
    scan_partial_kernel<<<nchunks, 1024, 0, stream>>>(blockhist, partial, L);
    scan_topfinal_kernel<<<nchunks, 1024, 0, stream>>>(blockhist, partial, nchunks, flatscan, L);
    bucket_scatter<<<NB, 256, 0, stream>>>(srcv, dstv, flatscan, sorted, E, NB, NBUCK);
    bucket_finalize<<<NBUCK, 256, 0, stream>>>(sorted, flatscan, csr, row_ptr, dis, NB, n);

    gemm1_mfma<<<(n + 127) / 128, 512, 0, stream>>>(x, wt1, dis, g1, n);
    agg1_fused<<<(n + 3) / 4, 256, 0, stream>>>((const unsigned*)g1, row_ptr, csr, dis, b1, wt2, g2, n);
    agg2_kernel<<<(n + 3) / 4, 256, 0, stream>>>(g2, row_ptr, csr, dis, b2, out, n);
}

// Round 18
// 197.603 us; speedup vs baseline: 1.1346x; 1.1346x over previous
//
#include <hip/hip_runtime.h>

// ---------------------------------------------------------------------------
// GCN 2-layer forward on MI355X.
//  out = Ahat( relu( Ahat (X W1) + b1 ) W2 ) + b2,  Ahat = D^-1/2 (A+I) D^-1/2
// R18: base = R16 (206us best; fusion reverted — per-block barrier coupled
//      wave lifetimes to max node degree, +36us). ONE change: Wt pre-swizzled
//      into MFMA FRAGMENT ORDER (frag = 64 lanes x 8 bf16 contiguous), so a
//      wave's B-load is one coalesced 1KB transaction instead of 16 scattered
//      512B-strided lines. Tests the last untouched invariant of gemm1's
//      64us across 6 structures: B-operand request scatter.
// ---------------------------------------------------------------------------

constexpr int IN_CH  = 256;
constexpr int HID    = 128;
constexpr int OUT_CH = 64;
constexpr int EPB = 4096;         // edges per block in hist/scatter

typedef __attribute__((ext_vector_type(8))) short short8;
typedef __attribute__((ext_vector_type(4))) float f32x4;

union F8 {                       // one MFMA A/B fragment: 8 bf16
    short8 v;
    unsigned short u[8];
    uint4  q;
};

// ---- bf16 helpers (RNE) ----
__device__ inline unsigned short f2b(float f) {
    unsigned u = __float_as_uint(f);
    u += 0x7fffu + ((u >> 16) & 1u);
    return (unsigned short)(u >> 16);
}
__device__ inline unsigned pack_bf16(float a, float b) {
    unsigned ua = __float_as_uint(a); ua += 0x7fffu + ((ua >> 16) & 1u);
    unsigned ub = __float_as_uint(b); ub += 0x7fffu + ((ub >> 16) & 1u);
    return (ua >> 16) | (ub & 0xffff0000u);
}
__device__ inline float2 unpack_bf16(unsigned v) {
    return make_float2(__uint_as_float(v << 16), __uint_as_float(v & 0xffff0000u));
}

// ---------------- CSR build (bucket radix, LDS atomics only) ----------------
// Fused: weights -> bf16 W^T in MFMA FRAGMENT ORDER.
// wf1[i]: j=i&7, lane=(i>>3)&63, ks=(i>>9)&7, cg=i>>12 (0..7);
//         col=cg*16+(lane&15), k=ks*32+(lane>>4)*8+j; value=W1[k][col].
// wf2[i]: j=i&7, lane=(i>>3)&63, ks=(i>>9)&3, cg=i>>11 (0..3);
//         col=cg*16+(lane&15), k=ks*32+(lane>>4)*8+j; value=W2[k][col].

__global__ __launch_bounds__(256) void bucket_hist(
    const int* __restrict__ dst, int* __restrict__ blockhist,
    const float* __restrict__ W1, unsigned short* __restrict__ wf1,
    const float* __restrict__ W2, unsigned short* __restrict__ wf2,
    int E, int NB, int NBUCK) {
    __shared__ int lbin[512];
    for (int l = threadIdx.x; l < 512; l += 256) lbin[l] = 0;
    __syncthreads();
    constexpr int NWT1 = IN_CH * HID;      // 32768
    constexpr int NWT2 = HID * OUT_CH;     // 8192
    for (int i = blockIdx.x * 256 + threadIdx.x; i < NWT1 + NWT2; i += gridDim.x * 256) {
        if (i < NWT1) {
            int j = i & 7, lane = (i >> 3) & 63, ks = (i >> 9) & 7, cg = i >> 12;
            int col = cg * 16 + (lane & 15);
            int k   = ks * 32 + (lane >> 4) * 8 + j;
            wf1[i] = f2b(W1[k * HID + col]);
        } else {
            int ii = i - NWT1;
            int j = ii & 7, lane = (ii >> 3) & 63, ks = (ii >> 9) & 3, cg = ii >> 11;
            int col = cg * 16 + (lane & 15);
            int k   = ks * 32 + (lane >> 4) * 8 + j;
            wf2[ii] = f2b(W2[k * OUT_CH + col]);
        }
    }
    int base = blockIdx.x * EPB;
    #pragma unroll 4
    for (int j = 0; j < EPB / 256; ++j) {
        int e = base + j * 256 + threadIdx.x;
        if (e < E) atomicAdd(&lbin[((unsigned)dst[e]) >> 8], 1);
    }
    __syncthreads();
    for (int l = threadIdx.x; l < NBUCK; l += 256)
        blockhist[l * NB + blockIdx.x] = lbin[l];   // bucket-major
}

__global__ __launch_bounds__(1024) void scan_partial_kernel(
    const int* __restrict__ in, int* __restrict__ partial, int len) {
    __shared__ int sh[1024];
    int i = blockIdx.x * 1024 + threadIdx.x;
    sh[threadIdx.x] = (i < len) ? in[i] : 0;
    __syncthreads();
    for (int ofs = 512; ofs > 0; ofs >>= 1) {
        if (threadIdx.x < ofs) sh[threadIdx.x] += sh[threadIdx.x + ofs];
        __syncthreads();
    }
    if (threadIdx.x == 0) partial[blockIdx.x] = sh[0];
}

__global__ __launch_bounds__(1024) void scan_topfinal_kernel(
    const int* __restrict__ in, const int* __restrict__ partial,
    int nchunks, int* __restrict__ out, int L) {
    __shared__ int top[1024];
    __shared__ int sh[1024];
    int t = threadIdx.x;
    top[t] = (t < nchunks) ? partial[t] : 0;
    int i = blockIdx.x * 1024 + t;
    int v = (i < L) ? in[i] : 0;
    sh[t] = v;
    __syncthreads();
    for (int ofs = 1; ofs < 1024; ofs <<= 1) {
        int a = (t >= ofs) ? top[t - ofs] : 0;
        int b = (t >= ofs) ? sh[t - ofs] : 0;
        __syncthreads();
        top[t] += a; sh[t] += b;
        __syncthreads();
    }
    int base = (blockIdx.x > 0) ? top[blockIdx.x - 1] : 0;   // exclusive chunk base
    if (i < L) out[i] = base + sh[t] - v;                    // exclusive
    if (blockIdx.x == 0 && t == 0) out[L] = top[nchunks - 1];  // grand total == E
}

__global__ __launch_bounds__(256) void bucket_scatter(
    const int* __restrict__ src, const int* __restrict__ dst,
    const int* __restrict__ flatscan, unsigned* __restrict__ sorted,
    int E, int NB, int NBUCK) {
    __shared__ int cur[512];
    for (int l = threadIdx.x; l < NBUCK; l += 256)
        cur[l] = flatscan[l * NB + blockIdx.x];
    __syncthreads();
    int base = blockIdx.x * EPB;
    #pragma unroll 4
    for (int j = 0; j < EPB / 256; ++j) {
        int e = base + j * 256 + threadIdx.x;
        if (e < E) {
            int d = dst[e];
            int bk = ((unsigned)d) >> 8;
            int slot = atomicAdd(&cur[bk], 1);
            sorted[slot] = (((unsigned)(d & 255)) << 24) | (unsigned)src[e];
        }
    }
}

__global__ __launch_bounds__(256) void bucket_finalize(
    const unsigned* __restrict__ sorted, const int* __restrict__ flatscan,
    int* __restrict__ csr_src, int* __restrict__ row_ptr, float* __restrict__ dis,
    int NB, int n) {
    __shared__ int cnt[256];
    __shared__ int sh[256];
    __shared__ int cur[256];
    int b = blockIdx.x;
    int t = threadIdx.x;
    int ebeg = flatscan[b * NB];
    int eend = flatscan[(b + 1) * NB];
    cnt[t] = 0;
    __syncthreads();
    for (int e = ebeg + t; e < eend; e += 256)
        atomicAdd(&cnt[sorted[e] >> 24], 1);
    __syncthreads();
    int v = cnt[t];
    sh[t] = v;
    __syncthreads();
    for (int ofs = 1; ofs < 256; ofs <<= 1) {
        int tv = (t >= ofs) ? sh[t - ofs] : 0;
        __syncthreads();
        sh[t] += tv;
        __syncthreads();
    }
    int excl = sh[t] - v;
    int node = b * 256 + t;
    if (node <= n) row_ptr[node] = ebeg + excl;
    if (node < n)  dis[node] = rsqrtf(1.0f + (float)v);
    cur[t] = excl;
    __syncthreads();
    for (int e = ebeg + t; e < eend; e += 256) {
        unsigned s = sorted[e];
        int pos = atomicAdd(&cur[s >> 24], 1);
        csr_src[ebeg + pos] = (int)(s & 0xFFFFFFu);
    }
}

// ---------------- GEMM 1 (R16 body; B from fragment-ordered wf1) -------------
// Tile 128x128, 8 waves (2M x 4N), BK=32, reg-prefetch double-buffer.

__global__ __launch_bounds__(512) void gemm1_mfma(
    const float* __restrict__ X, const unsigned short* __restrict__ Wf,
    const float* __restrict__ dis, unsigned short* __restrict__ G, int n) {
    constexpr int K = 256, LP = 20, NS = 8;
    __shared__ unsigned xs[2][128 * LP];          // 20 KB; reused by epilogue

    int tid  = threadIdx.x;
    int lane = tid & 63;
    int w    = tid >> 6;
    int wm = w >> 2, wn = w & 3;
    int rowbase = blockIdx.x * 128 + wm * 64;
    int colbase = wn * 32;
    int la = lane & 15, lb = lane >> 4;

    int srow = tid >> 2, sq = tid & 3;
    int grow = blockIdx.x * 128 + srow;
    if (grow >= n) grow = n - 1;
    const float* xrow = X + (size_t)grow * K + sq * 8;
    int sofs = srow * LP + sq * 4;                // uint offset in xs

    float4 pf0, pf1;
    #define G1_LOAD(ks) { const float* p_ = xrow + (ks) * 32;                 \
        pf0 = *(const float4*)(p_); pf1 = *(const float4*)(p_ + 4); }
    #define G1_WRITE(buf) { uint4 o_;                                         \
        o_.x = pack_bf16(pf0.x, pf0.y); o_.y = pack_bf16(pf0.z, pf0.w);       \
        o_.z = pack_bf16(pf1.x, pf1.y); o_.w = pack_bf16(pf1.z, pf1.w);       \
        *(uint4*)&xs[buf][sofs] = o_; }

    f32x4 acc[4][2];
    #pragma unroll
    for (int m = 0; m < 4; ++m)
        #pragma unroll
        for (int nn = 0; nn < 2; ++nn) acc[m][nn] = (f32x4){0.f, 0.f, 0.f, 0.f};

    G1_LOAD(0);
    G1_WRITE(0);
    G1_LOAD(1);
    __syncthreads();

    #pragma unroll
    for (int ks = 0; ks < NS; ++ks) {
        int cur = ks & 1;
        if (ks + 1 < NS) G1_WRITE(cur ^ 1);       // regs hold slab ks+1
        if (ks + 2 < NS) G1_LOAD(ks + 2);
        F8 a[4], b[2];
        #pragma unroll
        for (int m = 0; m < 4; ++m)
            a[m].q = *(const uint4*)&xs[cur][(wm * 64 + m * 16 + la) * LP + lb * 4];
        #pragma unroll
        for (int nn = 0; nn < 2; ++nn) {
            int cg = wn * 2 + nn;                 // col group 0..7
            b[nn].q = *(const uint4*)(Wf + (((size_t)cg * 8 + ks) * 64 + lane) * 8);
        }
        #pragma unroll
        for (int m = 0; m < 4; ++m)
            #pragma unroll
            for (int nn = 0; nn < 2; ++nn)
                acc[m][nn] = __builtin_amdgcn_mfma_f32_16x16x32_bf16(
                    a[m].v, b[nn].v, acc[m][nn], 0, 0, 0);
        __syncthreads();
    }
    #undef G1_LOAD
    #undef G1_WRITE

    // ---- epilogue: LDS transpose -> coalesced 32B stores, 2 row-half passes
    unsigned short* eps = (unsigned short*)&xs[0][0];
    constexpr int ES = 136;                       // ushort stride (272B, 16B-aligned)
    #pragma unroll
    for (int p = 0; p < 2; ++p) {
        __syncthreads();
        if (wm == p) {
            #pragma unroll
            for (int m = 0; m < 4; ++m) {
                int lr0 = m * 16 + lb * 4;
                int r0 = rowbase + lr0;           // rowbase already includes wm*64
                float dv[4];
                #pragma unroll
                for (int r = 0; r < 4; ++r) dv[r] = (r0 + r < n) ? dis[r0 + r] : 0.f;
                #pragma unroll
                for (int nn = 0; nn < 2; ++nn) {
                    int col = colbase + nn * 16 + la;
                    #pragma unroll
                    for (int r = 0; r < 4; ++r)
                        eps[(lr0 + r) * ES + col] = f2b(acc[m][nn][r] * dv[r]);
                }
            }
        }
        __syncthreads();
        {
            int lrow = tid >> 3, seg = tid & 7;   // 64 rows x 8 segs x 16 ushorts
            int gr = blockIdx.x * 128 + p * 64 + lrow;
            if (gr < n) {
                const uint4* s = (const uint4*)&eps[lrow * ES + seg * 16];
                uint4 v0 = s[0], v1 = s[1];
                uint4* d = (uint4*)(G + (size_t)gr * HID + seg * 16);
                d[0] = v0; d[1] = v1;
            }
        }
    }
}

// ---------------- GEMM 2 (R16 body; B from fragment-ordered wf2) -------------
// Tile 256x64, 8 waves (4M x 2N), BK=32.

__global__ __launch_bounds__(512) void gemm2_mfma(
    const unsigned short* __restrict__ H, const unsigned short* __restrict__ Wf,
    const float* __restrict__ dis, unsigned short* __restrict__ G, int n) {
    constexpr int K = 128, LP = 20, NS = 4;
    __shared__ unsigned xs[2][256 * LP];          // 40 KB; reused by epilogue

    int tid  = threadIdx.x;
    int lane = tid & 63;
    int w    = tid >> 6;
    int wm = w >> 1, wn = w & 1;
    int rowbase = blockIdx.x * 256 + wm * 64;
    int colbase = wn * 32;
    int la = lane & 15, lb = lane >> 4;

    const unsigned* Hu = (const unsigned*)H;      // 64 uints per row

    int sr0 = tid >> 2, sq0 = tid & 3;
    int sr1 = (tid + 512) >> 2, sq1 = tid & 3;
    int g0 = blockIdx.x * 256 + sr0; g0 = g0 < n ? g0 : n - 1;
    int g1 = blockIdx.x * 256 + sr1; g1 = g1 < n ? g1 : n - 1;

    uint4 pf0, pf1;
    #define G2_LOAD(ks) {                                                     \
        pf0 = *(const uint4*)&Hu[(size_t)g0 * 64 + (ks) * 16 + sq0 * 4];      \
        pf1 = *(const uint4*)&Hu[(size_t)g1 * 64 + (ks) * 16 + sq1 * 4]; }
    #define G2_WRITE(buf) {                                                   \
        *(uint4*)&xs[buf][sr0 * LP + sq0 * 4] = pf0;                          \
        *(uint4*)&xs[buf][sr1 * LP + sq1 * 4] = pf1; }

    f32x4 acc[4][2];
    #pragma unroll
    for (int m = 0; m < 4; ++m)
        #pragma unroll
        for (int nn = 0; nn < 2; ++nn) acc[m][nn] = (f32x4){0.f, 0.f, 0.f, 0.f};

    G2_LOAD(0);
    G2_WRITE(0);
    G2_LOAD(1);
    __syncthreads();

    #pragma unroll
    for (int ks = 0; ks < NS; ++ks) {
        int cur = ks & 1;
        if (ks + 1 < NS) G2_WRITE(cur ^ 1);
        if (ks + 2 < NS) G2_LOAD(ks + 2);
        F8 a[4], b[2];
        #pragma unroll
        for (int m = 0; m < 4; ++m)
            a[m].q = *(const uint4*)&xs[cur][(wm * 64 + m * 16 + la) * LP + lb * 4];
        #pragma unroll
        for (int nn = 0; nn < 2; ++nn) {
            int cg = wn * 2 + nn;                 // col group 0..3
            b[nn].q = *(const uint4*)(Wf + (((size_t)cg * 4 + ks) * 64 + lane) * 8);
        }
        #pragma unroll
        for (int m = 0; m < 4; ++m)
            #pragma unroll
            for (int nn = 0; nn < 2; ++nn)
                acc[m][nn] = __builtin_amdgcn_mfma_f32_16x16x32_bf16(
                    a[m].v, b[nn].v, acc[m][nn], 0, 0, 0);
        __syncthreads();
    }
    #undef G2_LOAD
    #undef G2_WRITE

    // ---- epilogue: LDS transpose -> coalesced 32B stores, 2 passes of 128 rows
    unsigned short* eps = (unsigned short*)&xs[0][0];
    constexpr int ES = 72;                        // ushort stride (144B, 16B-aligned)
    #pragma unroll
    for (int p = 0; p < 2; ++p) {
        __syncthreads();
        if ((wm >> 1) == p) {
            #pragma unroll
            for (int m = 0; m < 4; ++m) {
                int lr0 = (wm & 1) * 64 + m * 16 + lb * 4;
                int r0 = rowbase + m * 16 + lb * 4;
                float dv[4];
                #pragma unroll
                for (int r = 0; r < 4; ++r) dv[r] = (r0 + r < n) ? dis[r0 + r] : 0.f;
                #pragma unroll
                for (int nn = 0; nn < 2; ++nn) {
                    int col = colbase + nn * 16 + la;
                    #pragma unroll
                    for (int r = 0; r < 4; ++r)
                        eps[(lr0 + r) * ES + col] = f2b(acc[m][nn][r] * dv[r]);
                }
            }
        }
        __syncthreads();
        {
            int lrow = tid >> 2, seg = tid & 3;   // 128 rows x 4 segs x 16 ushorts
            int gr = blockIdx.x * 256 + p * 128 + lrow;
            if (gr < n) {
                const uint4* s = (const uint4*)&eps[lrow * ES + seg * 16];
                uint4 v0 = s[0], v1 = s[1];
                uint4* d = (uint4*)(G + (size_t)gr * OUT_CH + seg * 16);
                d[0] = v0; d[1] = v1;
            }
        }
    }
}

// ---------------- Aggregation 1: h1 = bf16(relu(dis .* (self+gather) + b1)) --
// Quarter-wave per edge: 16 lanes x uint4 = 256B row; 16 gathers in flight.

__device__ inline void acc8(float* s, uint4 u) {
    float2 t;
    t = unpack_bf16(u.x); s[0] += t.x; s[1] += t.y;
    t = unpack_bf16(u.y); s[2] += t.x; s[3] += t.y;
    t = unpack_bf16(u.z); s[4] += t.x; s[5] += t.y;
    t = unpack_bf16(u.w); s[6] += t.x; s[7] += t.y;
}

__global__ __launch_bounds__(256) void agg1_kernel(
    const unsigned* __restrict__ G, const int* __restrict__ row_ptr,
    const int* __restrict__ csr_src, const float* __restrict__ dis,
    const float* __restrict__ b1, unsigned* __restrict__ H, int n) {
    int wid = (blockIdx.x * blockDim.x + threadIdx.x) >> 6;
    int lane = threadIdx.x & 63;
    if (wid >= n) return;
    int q = lane >> 4, hl = lane & 15;
    const char* Gb = (const char*)G;              // row = 256B
    unsigned lofs = (unsigned)(hl << 4);
    float s0[8] = {0,0,0,0,0,0,0,0}, s1[8] = {0,0,0,0,0,0,0,0};
    float s2[8] = {0,0,0,0,0,0,0,0}, s3[8] = {0,0,0,0,0,0,0,0};
    int beg = row_ptr[wid], end = row_ptr[wid + 1];
    for (int base = beg; base < end; base += 64) {
        int m = end - base; if (m > 64) m = 64;
        int idx = csr_src[base + (lane < m ? lane : m - 1)];
        int j = 0;
        for (; j + 16 <= m; j += 16) {
            unsigned o0 = ((unsigned)__shfl(idx, j +      q) << 8) + lofs;
            unsigned o1 = ((unsigned)__shfl(idx, j +  4 + q) << 8) + lofs;
            unsigned o2 = ((unsigned)__shfl(idx, j +  8 + q) << 8) + lofs;
            unsigned o3 = ((unsigned)__shfl(idx, j + 12 + q) << 8) + lofs;
            uint4 u0 = *(const uint4*)(Gb + o0);
            uint4 u1 = *(const uint4*)(Gb + o1);
            uint4 u2 = *(const uint4*)(Gb + o2);
            uint4 u3 = *(const uint4*)(Gb + o3);
            acc8(s0, u0); acc8(s1, u1); acc8(s2, u2); acc8(s3, u3);
        }
        for (; j + 4 <= m; j += 4) {
            unsigned o0 = ((unsigned)__shfl(idx, j + q) << 8) + lofs;
            uint4 u0 = *(const uint4*)(Gb + o0);
            acc8(s0, u0);
        }
        int rem = m - j;                          // 0..3
        if (rem) {
            int ii = __shfl(idx, j + (q < rem ? q : 0));
            if (q < rem) {
                uint4 u = *(const uint4*)(Gb + (((unsigned)ii << 8) + lofs));
                acc8(s0, u);
            }
        }
    }
    #pragma unroll
    for (int c = 0; c < 8; ++c) s0[c] += s1[c] + s2[c] + s3[c];
    #pragma unroll
    for (int c = 0; c < 8; ++c) {
        s0[c] += __shfl_xor(s0[c], 16);
        s0[c] += __shfl_xor(s0[c], 32);
    }
    uint4 su = *(const uint4*)(Gb + (((unsigned)wid << 8) + lofs));   // self
    acc8(s0, su);
    float d = dis[wid];
    float bb[8];
    *(float4*)&bb[0] = ((const float4*)b1)[hl * 2];
    *(float4*)&bb[4] = ((const float4*)b1)[hl * 2 + 1];
    float o[8];
    #pragma unroll
    for (int c = 0; c < 8; ++c) o[c] = fmaxf(fmaf(s0[c], d, bb[c]), 0.f);
    if (q == 0) {
        uint4 ou;
        ou.x = pack_bf16(o[0], o[1]);
        ou.y = pack_bf16(o[2], o[3]);
        ou.z = pack_bf16(o[4], o[5]);
        ou.w = pack_bf16(o[6], o[7]);
        *(uint4*)((char*)H + (((unsigned)wid << 8) + lofs)) = ou;
    }
}

// ---------------- Aggregation 2: out = dis .* (self+gather) + b2 -------------

__device__ inline void acc4u(float* s, uint2 u) {
    float2 t;
    t = unpack_bf16(u.x); s[0] += t.x; s[1] += t.y;
    t = unpack_bf16(u.y); s[2] += t.x; s[3] += t.y;
}

__global__ __launch_bounds__(256) void agg2_kernel(
    const unsigned short* __restrict__ G, const int* __restrict__ row_ptr,
    const int* __restrict__ csr_src, const float* __restrict__ dis,
    const float* __restrict__ b2, float* __restrict__ out, int n) {
    int wid = (blockIdx.x * blockDim.x + threadIdx.x) >> 6;
    int lane = threadIdx.x & 63;
    if (wid >= n) return;
    int q = lane >> 4, hl = lane & 15;
    const char* Gb = (const char*)G;              // row = 128B
    unsigned lofs = (unsigned)(hl << 3);
    float s0[4] = {0,0,0,0}, s1[4] = {0,0,0,0}, s2[4] = {0,0,0,0}, s3[4] = {0,0,0,0};
    int beg = row_ptr[wid], end = row_ptr[wid + 1];
    for (int base = beg; base < end; base += 64) {
        int m = end - base; if (m > 64) m = 64;
        int idx = csr_src[base + (lane < m ? lane : m - 1)];
        int j = 0;
        for (; j + 16 <= m; j += 16) {
            unsigned o0 = ((unsigned)__shfl(idx, j +      q) << 7) + lofs;
            unsigned o1 = ((unsigned)__shfl(idx, j +  4 + q) << 7) + lofs;
            unsigned o2 = ((unsigned)__shfl(idx, j +  8 + q) << 7) + lofs;
            unsigned o3 = ((unsigned)__shfl(idx, j + 12 + q) << 7) + lofs;
            uint2 u0 = *(const uint2*)(Gb + o0);
            uint2 u1 = *(const uint2*)(Gb + o1);
            uint2 u2 = *(const uint2*)(Gb + o2);
            uint2 u3 = *(const uint2*)(Gb + o3);
            acc4u(s0, u0); acc4u(s1, u1); acc4u(s2, u2); acc4u(s3, u3);
        }
        for (; j + 4 <= m; j += 4) {
            unsigned o0 = ((unsigned)__shfl(idx, j + q) << 7) + lofs;
            uint2 u0 = *(const uint2*)(Gb + o0);
            acc4u(s0, u0);
        }
        int rem = m - j;
        if (rem) {
            int ii = __shfl(idx, j + (q < rem ? q : 0));
            if (q < rem) {
                uint2 u = *(const uint2*)(Gb + (((unsigned)ii << 7) + lofs));
                acc4u(s0, u);
            }
        }
    }
    #pragma unroll
    for (int c = 0; c < 4; ++c) s0[c] += s1[c] + s2[c] + s3[c];
    #pragma unroll
    for (int c = 0; c < 4; ++c) {
        s0[c] += __shfl_xor(s0[c], 16);
        s0[c] += __shfl_xor(s0[c], 32);
    }
    uint2 su = *(const uint2*)(Gb + (((unsigned)wid << 7) + lofs));   // self
    acc4u(s0, su);
    float d = dis[wid];
    float4 bb = ((const float4*)b2)[hl];
    if (q == 0) {
        float4 o;
        o.x = fmaf(s0[0], d, bb.x);
        o.y = fmaf(s0[1], d, bb.y);
        o.z = fmaf(s0[2], d, bb.z);
        o.w = fmaf(s0[3], d, bb.w);
        ((float4*)out)[(size_t)wid * 16 + hl] = o;
    }
}

// ---------------- launch ----------------

extern "C" void kernel_launch(void* const* d_in, const int* in_sizes, int n_in,
                              void* d_out, int out_size, void* d_ws, size_t ws_size,
                              hipStream_t stream) {
    const float* x  = (const float*)d_in[0];
    const int*   ei = (const int*)d_in[1];
    const float* W1 = (const float*)d_in[2];
    const float* b1 = (const float*)d_in[3];
    const float* W2 = (const float*)d_in[4];
    const float* b2 = (const float*)d_in[5];
    float* out = (float*)d_out;

    int n = in_sizes[0] / IN_CH;       // 100000
    int E = in_sizes[1] / 2;           // 1600000
    const int* srcv = ei;
    const int* dstv = ei + E;

    int NB    = (E + EPB - 1) / EPB;   // 391 edge-blocks
    int NBUCK = (n + 255) >> 8;        // 391 buckets (256 nodes each)
    int L     = NBUCK * NB;
    int nchunks = (L + 1023) / 1024;   // 150

    char* w = (char*)d_ws;
    unsigned short* g1 = (unsigned short*)w;  w += (size_t)n * HID * 2;   // 25.6 MB
    unsigned short* h1 = (unsigned short*)w;  w += (size_t)n * HID * 2;   // 25.6 MB
    unsigned short* g2 = g1;                                              // overlay
    unsigned short* wf1 = (unsigned short*)w; w += (size_t)IN_CH * HID * 2;
    unsigned short* wf2 = (unsigned short*)w; w += (size_t)HID * OUT_CH * 2;
    int*      blockhist = (int*)w; w += (size_t)L * 4;
    int*      flatscan  = (int*)w; w += (size_t)(L + 1) * 4;
    int*      partial   = (int*)w; w += (size_t)1024 * 4;
    unsigned* sorted    = (unsigned*)w; w += (size_t)E * 4;               // 6.4 MB
    int*      csr       = (int*)w; w += (size_t)E * 4;                    // 6.4 MB
    int*      row_ptr   = (int*)w; w += (size_t)(n + 1) * 4;
    float*    dis       = (float*)w; w += (size_t)n * 4;

    bucket_hist<<<NB, 256, 0, stream>>>(dstv, blockhist, W1, wf1, W2, wf2, E, NB, NBUCK);
    scan_partial_kernel<<<nchunks, 1024, 0, stream>>>(blockhist, partial, L);
    scan_topfinal_kernel<<<nchunks, 1024, 0, stream>>>(blockhist, partial, nchunks, flatscan, L);
    bucket_scatter<<<NB, 256, 0, stream>>>(srcv, dstv, flatscan, sorted, E, NB, NBUCK);
    bucket_finalize<<<NBUCK, 256, 0, stream>>>(sorted, flatscan, csr, row_ptr, dis, NB, n);

    gemm1_mfma<<<(n + 127) / 128, 512, 0, stream>>>(x, wf1, dis, g1, n);
    agg1_kernel<<<(n + 3) / 4, 256, 0, stream>>>((const unsigned*)g1, row_ptr, csr, dis, b1, (unsigned*)h1, n);
    gemm2_mfma<<<(n + 255) / 256, 512, 0, stream>>>(h1, wf2, dis, g2, n);
    agg2_kernel<<<(n + 3) / 4, 256, 0, stream>>>(g2, row_ptr, csr, dis, b2, out, n);
}